// Round 4
// baseline (12048.653 us; speedup 1.0000x reference)
//
#include <hip/hip_runtime.h>
#include <hip/hip_bf16.h>
#include <math.h>

#define BB 4
#define SS 4096
#define DDIM 1024
#define KSEL 8
#define NR 16
#define NC 16
#define MID 256
#define RC 256
#define TOK (BB*SS)

#define TQ 64
#define TK 32
#define DSL 256

typedef __hip_bfloat16 bf16;

__device__ __forceinline__ float uihf(unsigned v) { union { unsigned i; float f; } t; t.i = v; return t.f; }
__device__ __forceinline__ float b2f(bf16 h) { return __bfloat162float(h); }
// dual-dtype scalar load: flag!=0 -> f32 buffer, else bf16 buffer
__device__ __forceinline__ float loadf(const void* p, size_t i, bool f32m) {
    return f32m ? ((const float*)p)[i] : b2f(((const bf16*)p)[i]);
}

// ws layout (float offsets). Total ~18 MB.
#define WS_FLAGS 0                          // 16 ints
#define WS_RB   16                          // [16][256] f32
#define WS_CB2  (WS_RB + NR*MID)            // [16][256] f32
#define WS_CB1  (WS_CB2 + NC*MID)           // [16][1024] f32
#define WS_CW   (WS_CB1 + NC*DDIM)          // [TOK][16] f32
#define WS_L    (WS_CW + (size_t)TOK*NC)    // [TOK] f32
#define WS_QK   (WS_L + TOK)                // bf16 area: Q [TOK][256] then KK [TOK][256]

struct DetectArgs { const void* p[9]; int n[9]; };

// ---------------- dtype detector ----------------
__global__ void k_detect(DetectArgs A, int* __restrict__ flags) {
    int b = blockIdx.x;                      // one block per input
    const unsigned short* u = (const unsigned short*)A.p[b];
    int n = A.n[b]; if (n > 4096) n = 4096;
    int tid = threadIdx.x;
    float m = 0.f;
    for (int i = tid; i < n; i += 256) {
        unsigned v = (((unsigned)u[i]) << 16) & 0x7fffffffu;
        float f = uihf(v);
        if (f == f) m = fmaxf(m, f);         // skip NaN patterns
    }
    for (int o = 32; o; o >>= 1) m = fmaxf(m, __shfl_xor(m, o));
    __shared__ float red[4];
    if ((tid & 63) == 0) red[tid >> 6] = m;
    __syncthreads();
    if (tid == 0) {
        float mm = fmaxf(fmaxf(red[0], red[1]), fmaxf(red[2], red[3]));
        flags[b] = (b == 1) ? 0 : (mm > 1e4f ? 1 : 0);   // input 1 = int32 indices
    }
}

// ---------------- basis sums ----------------
__global__ void k_rbsum(const void* __restrict__ rb, float* __restrict__ ws) {
    bool f32m = ((const int*)ws)[4] != 0;
    int r = blockIdx.x, m = threadIdx.x;
    size_t base = (size_t)r*DDIM*MID + m;
    float s = 0.f;
    #pragma unroll 8
    for (int d = 0; d < DDIM; ++d) s += loadf(rb, base + (size_t)d*MID, f32m);
    ws[WS_RB + r*MID + m] = s;
}

__global__ void k_cb2(const void* __restrict__ cb, float* __restrict__ ws) {
    bool f32m = ((const int*)ws)[5] != 0;
    int row = blockIdx.x*4 + (threadIdx.x >> 6);   // row = c*256+m, 4096 rows
    int lane = threadIdx.x & 63;
    size_t base = (size_t)row*DDIM;
    float s = 0.f;
    for (int i = lane; i < DDIM; i += 64) s += loadf(cb, base + i, f32m);
    for (int o = 32; o; o >>= 1) s += __shfl_down(s, o);
    if (lane == 0) ws[WS_CB2 + row] = s;
}

__global__ void k_cb1(const void* __restrict__ cb, float* __restrict__ ws) {
    bool f32m = ((const int*)ws)[5] != 0;
    int c = blockIdx.x >> 2;
    int d = ((blockIdx.x & 3) << 8) + threadIdx.x;
    size_t base = (size_t)c*MID*DDIM + d;
    float s = 0.f;
    #pragma unroll 8
    for (int m = 0; m < MID; ++m) s += loadf(cb, base + (size_t)m*DDIM, f32m);
    ws[WS_CB1 + c*DDIM + d] = s;
}

// ---------------- routing: per-token q, kk, col_w ----------------
__global__ __launch_bounds__(256) void k_route(const int* __restrict__ nidx,
        const void* __restrict__ nw, const void* __restrict__ rmat,
        float* __restrict__ ws) {
    bool f2 = ((const int*)ws)[2] != 0, f3 = ((const int*)ws)[3] != 0;
    int tok = blockIdx.x, tid = threadIdx.x;
    int wid = tid >> 6, lane = tid & 63;
    __shared__ float red[4];
    __shared__ float bval;
    __shared__ int   sidx[KSEL];
    __shared__ float sw[KSEL];
    __shared__ float rec[RC];
    __shared__ float rw[NR], cw[NC];
    if (tid < KSEL) { sidx[tid] = nidx[tok*KSEL + tid]; sw[tid] = loadf(nw, tok*KSEL + tid, f2); }
    __syncthreads();

    float acc = 0.f;
    #pragma unroll 1
    for (int k = 0; k < KSEL; ++k) {
        float v = loadf(rmat, sidx[k]*RC + tid, f3);
        float r = v;
        r = fmaxf(r, __shfl_xor(r,32)); r = fmaxf(r, __shfl_xor(r,16));
        r = fmaxf(r, __shfl_xor(r, 8)); r = fmaxf(r, __shfl_xor(r, 4));
        r = fmaxf(r, __shfl_xor(r, 2)); r = fmaxf(r, __shfl_xor(r, 1));
        if (lane == 0) red[wid] = r;
        __syncthreads();
        if (tid == 0) bval = fmaxf(fmaxf(red[0],red[1]), fmaxf(red[2],red[3]));
        __syncthreads();
        float e = __expf(v - bval);
        float s = e;
        s += __shfl_xor(s,32); s += __shfl_xor(s,16); s += __shfl_xor(s,8);
        s += __shfl_xor(s, 4); s += __shfl_xor(s, 2); s += __shfl_xor(s,1);
        if (lane == 0) red[wid] = s;
        __syncthreads();
        if (tid == 0) bval = red[0]+red[1]+red[2]+red[3];
        __syncthreads();
        acc += sw[k] * e / bval;
    }
    {
        float r = acc;
        r = fmaxf(r, __shfl_xor(r,32)); r = fmaxf(r, __shfl_xor(r,16));
        r = fmaxf(r, __shfl_xor(r, 8)); r = fmaxf(r, __shfl_xor(r, 4));
        r = fmaxf(r, __shfl_xor(r, 2)); r = fmaxf(r, __shfl_xor(r, 1));
        if (lane == 0) red[wid] = r;
        __syncthreads();
        if (tid == 0) bval = fmaxf(fmaxf(red[0],red[1]), fmaxf(red[2],red[3]));
        __syncthreads();
        float e = __expf(acc - bval);
        float s = e;
        s += __shfl_xor(s,32); s += __shfl_xor(s,16); s += __shfl_xor(s,8);
        s += __shfl_xor(s, 4); s += __shfl_xor(s, 2); s += __shfl_xor(s,1);
        if (lane == 0) red[wid] = s;
        __syncthreads();
        if (tid == 0) bval = red[0]+red[1]+red[2]+red[3];
        __syncthreads();
        rec[tid] = e / bval;
    }
    __syncthreads();
    if (tid < NR) {
        float s = 0.f;
        #pragma unroll
        for (int c = 0; c < NC; ++c) s += rec[tid*NC + c];
        rw[tid] = s;
    } else if (tid < 32) {
        int c = tid - 16;
        float s = 0.f;
        #pragma unroll
        for (int r = 0; r < NR; ++r) s += rec[r*NC + c];
        cw[c] = s;
        ws[WS_CW + (size_t)tok*NC + c] = s;
    }
    __syncthreads();
    float qv = 0.f, kv = 0.f;
    #pragma unroll
    for (int r = 0; r < NR; ++r) qv += rw[r] * ws[WS_RB + r*MID + tid];
    #pragma unroll
    for (int c = 0; c < NC; ++c) kv += cw[c] * ws[WS_CB2 + c*MID + tid];
    bf16* Qh  = (bf16*)(ws + WS_QK);
    bf16* KKh = Qh + (size_t)TOK*MID;
    Qh [(size_t)tok*MID + tid] = __float2bfloat16(qv * 0.0625f);  // fold 1/sqrt(256)
    KKh[(size_t)tok*MID + tid] = __float2bfloat16(kv);
}

// ---------------- pass A: softmax denominators (no max-sub; |scores|~0.03) --------
__global__ __launch_bounds__(256,1) void k_stats(float* __restrict__ ws) {
    __shared__ float qs[TQ][MID+4];
    __shared__ float ks[TK][MID+4];
    int b  = blockIdx.x >> 6;
    int q0 = (blockIdx.x & 63) * TQ;
    int tid = threadIdx.x;
    const bf16* Qh  = (const bf16*)(ws + WS_QK);
    const bf16* KKh = Qh + (size_t)TOK*MID;
    const bf16* qg = Qh + ((size_t)b*SS + q0)*MID;
    for (int i = tid; i < TQ*MID; i += 256) qs[i>>8][i&255] = b2f(qg[i]);

    int qh = tid >> 3, th = tid & 7;
    float l0 = 0.f, l1 = 0.f;
    int r0 = q0 + 2*qh, r1 = r0 + 1;
    const bf16* kg = KKh + (size_t)b*SS*MID;
    for (int t0 = 0; t0 < q0 + TQ; t0 += TK) {
        __syncthreads();
        for (int i = tid; i < TK*MID; i += 256) ks[i>>8][i&255] = b2f(kg[(size_t)t0*MID + i]);
        __syncthreads();
        float s0[4] = {0,0,0,0}, s1[4] = {0,0,0,0};
        for (int m = 0; m < MID; m += 4) {
            float4 a0 = *(const float4*)&qs[2*qh  ][m];
            float4 a1 = *(const float4*)&qs[2*qh+1][m];
            #pragma unroll
            for (int j = 0; j < 4; ++j) {
                float4 bv = *(const float4*)&ks[4*th+j][m];
                s0[j] += a0.x*bv.x + a0.y*bv.y + a0.z*bv.z + a0.w*bv.w;
                s1[j] += a1.x*bv.x + a1.y*bv.y + a1.z*bv.z + a1.w*bv.w;
            }
        }
        #pragma unroll
        for (int j = 0; j < 4; ++j) {
            int t = t0 + 4*th + j;
            if (t <= r0) l0 += __expf(s0[j]);
            if (t <= r1) l1 += __expf(s1[j]);
        }
    }
    l0 += __shfl_xor(l0,1); l0 += __shfl_xor(l0,2); l0 += __shfl_xor(l0,4);
    l1 += __shfl_xor(l1,1); l1 += __shfl_xor(l1,2); l1 += __shfl_xor(l1,4);
    if (th == 0) {
        ws[WS_L + (size_t)b*SS + r0] = l0;
        ws[WS_L + (size_t)b*SS + r1] = l1;
    }
}

// ------- pass B: context + transform + gelu -> U (stored in d_out, f32) --------
__global__ __launch_bounds__(256,1) void k_attn(const void* __restrict__ x,
        float* __restrict__ ws, const void* __restrict__ alphap,
        float* __restrict__ U) {
    __shared__ float qs[TQ][MID+4];
    __shared__ float ks[TK][MID+4];
    __shared__ float ps[TQ][TK+2];
    __shared__ float linv[TQ];
    __shared__ float cws[TQ][NC];
    __shared__ float cb1s[NC][DSL+4];
    bool xf32 = ((const int*)ws)[0] != 0, af32 = ((const int*)ws)[8] != 0;
    int qt = blockIdx.x, dsl = blockIdx.y, b = blockIdx.z;
    int q0 = qt*TQ, d0 = dsl*DSL;
    int tid = threadIdx.x;

    const bf16* Qh  = (const bf16*)(ws + WS_QK);
    const bf16* KKh = Qh + (size_t)TOK*MID;
    const bf16* qg = Qh + ((size_t)b*SS + q0)*MID;
    for (int i = tid; i < TQ*MID; i += 256) qs[i>>8][i&255] = b2f(qg[i]);
    if (tid < TQ) linv[tid] = 1.f / ws[WS_L + (size_t)b*SS + q0 + tid];
    for (int i = tid; i < TQ*NC; i += 256)
        cws[i>>4][i&15] = ws[WS_CW + ((size_t)b*SS + q0)*NC + i];
    for (int i = tid; i < NC*DSL; i += 256)
        cb1s[i>>8][i&255] = ws[WS_CB1 + (i>>8)*DDIM + d0 + (i&255)];

    float acc[4][16];
    #pragma unroll
    for (int j = 0; j < 4; ++j)
        #pragma unroll
        for (int i = 0; i < 16; ++i) acc[j][i] = 0.f;

    int qgr = tid >> 4, dg = tid & 15;
    const bf16* kg = KKh + (size_t)b*SS*MID;
    size_t xbase = (size_t)b*SS*DDIM + d0 + dg*16;

    for (int t0 = 0; t0 < q0 + TQ; t0 += TK) {
        __syncthreads();
        for (int i = tid; i < TK*MID; i += 256) ks[i>>8][i&255] = b2f(kg[(size_t)t0*MID + i]);
        __syncthreads();
        {   // scores -> probabilities
            int qh = tid >> 3, th = tid & 7;
            float s0[4] = {0,0,0,0}, s1[4] = {0,0,0,0};
            for (int m = 0; m < MID; m += 4) {
                float4 a0 = *(const float4*)&qs[2*qh  ][m];
                float4 a1 = *(const float4*)&qs[2*qh+1][m];
                #pragma unroll
                for (int j = 0; j < 4; ++j) {
                    float4 bv = *(const float4*)&ks[4*th+j][m];
                    s0[j] += a0.x*bv.x + a0.y*bv.y + a0.z*bv.z + a0.w*bv.w;
                    s1[j] += a1.x*bv.x + a1.y*bv.y + a1.z*bv.z + a1.w*bv.w;
                }
            }
            int r0 = q0 + 2*qh, r1 = r0 + 1;
            float li0 = linv[2*qh], li1 = linv[2*qh+1];
            #pragma unroll
            for (int j = 0; j < 4; ++j) {
                int t = t0 + 4*th + j;
                ps[2*qh  ][4*th+j] = (t <= r0) ? __expf(s0[j])*li0 : 0.f;
                ps[2*qh+1][4*th+j] = (t <= r1) ? __expf(s1[j])*li1 : 0.f;
            }
        }
        __syncthreads();
        #pragma unroll 2
        for (int tj = 0; tj < TK; ++tj) {
            float xv[16];
            if (xf32) {
                const float* xp = (const float*)x + xbase + (size_t)(t0+tj)*DDIM;
                float4 a = *(const float4*)(xp);
                float4 bq= *(const float4*)(xp+4);
                float4 c = *(const float4*)(xp+8);
                float4 d = *(const float4*)(xp+12);
                xv[0]=a.x; xv[1]=a.y; xv[2]=a.z; xv[3]=a.w;
                xv[4]=bq.x; xv[5]=bq.y; xv[6]=bq.z; xv[7]=bq.w;
                xv[8]=c.x; xv[9]=c.y; xv[10]=c.z; xv[11]=c.w;
                xv[12]=d.x; xv[13]=d.y; xv[14]=d.z; xv[15]=d.w;
            } else {
                const unsigned short* xp = (const unsigned short*)x + xbase + (size_t)(t0+tj)*DDIM;
                uint4 pa = *(const uint4*)(xp);
                uint4 pb = *(const uint4*)(xp + 8);
                xv[ 0]=uihf(pa.x<<16); xv[ 1]=uihf(pa.x&0xffff0000u);
                xv[ 2]=uihf(pa.y<<16); xv[ 3]=uihf(pa.y&0xffff0000u);
                xv[ 4]=uihf(pa.z<<16); xv[ 5]=uihf(pa.z&0xffff0000u);
                xv[ 6]=uihf(pa.w<<16); xv[ 7]=uihf(pa.w&0xffff0000u);
                xv[ 8]=uihf(pb.x<<16); xv[ 9]=uihf(pb.x&0xffff0000u);
                xv[10]=uihf(pb.y<<16); xv[11]=uihf(pb.y&0xffff0000u);
                xv[12]=uihf(pb.z<<16); xv[13]=uihf(pb.z&0xffff0000u);
                xv[14]=uihf(pb.w<<16); xv[15]=uihf(pb.w&0xffff0000u);
            }
            float p0 = ps[4*qgr  ][tj], p1 = ps[4*qgr+1][tj];
            float p2 = ps[4*qgr+2][tj], p3 = ps[4*qgr+3][tj];
            #pragma unroll
            for (int i = 0; i < 16; ++i) {
                acc[0][i] += p0*xv[i]; acc[1][i] += p1*xv[i];
                acc[2][i] += p2*xv[i]; acc[3][i] += p3*xv[i];
            }
        }
    }
    float al = af32 ? ((const float*)alphap)[0] : b2f(((const bf16*)alphap)[0]);
    #pragma unroll
    for (int j = 0; j < 4; ++j) {
        int lrow = 4*qgr + j;
        int row  = q0 + lrow;
        #pragma unroll
        for (int i = 0; i < 16; ++i) {
            int col = d0 + dg*16 + i;
            float tr = 0.f;
            #pragma unroll
            for (int c = 0; c < NC; ++c) tr += cws[lrow][c] * cb1s[c][dg*16 + i];
            float u = acc[j][i] + al*tr;
            u = u * 0.5f * (1.f + erff(u * 0.70710678118f));
            U[((size_t)b*SS + row)*DDIM + col] = u;
        }
    }
}

// --------- final GEMM, in-place over d_out (f32): out = gelu_U @ W^T + bias ----
// Each block owns 64 rows: stages all 64x1024 of U into LDS (as bf16) first,
// then overwrites those same rows. No cross-block hazard.
__global__ __launch_bounds__(256,1) void k_gemm2(float* __restrict__ out,
        const void* __restrict__ w, const void* __restrict__ bias,
        const float* __restrict__ ws) {
    __shared__ bf16 us[DDIM][66];            // us[k][m], 135 KB
    __shared__ float wsm[64][33];
    bool wf32 = ((const int*)ws)[6] != 0, bf32 = ((const int*)ws)[7] != 0;
    int m0 = blockIdx.x * 64;
    int tid = threadIdx.x;
    // stage U rows (vectorized float4 loads, convert to bf16 in LDS)
    for (int i = tid; i < 64*DDIM/4; i += 256) {
        int m = i >> 8, k4 = (i & 255) << 2;
        float4 v = *(const float4*)(out + (size_t)(m0+m)*DDIM + k4);
        us[k4+0][m] = __float2bfloat16(v.x);
        us[k4+1][m] = __float2bfloat16(v.y);
        us[k4+2][m] = __float2bfloat16(v.z);
        us[k4+3][m] = __float2bfloat16(v.w);
    }
    __syncthreads();

    int tm = tid >> 4, tn = tid & 15;
    for (int nc = 0; nc < DDIM/64; ++nc) {
        int n0 = nc * 64;
        float acc[4][4];
        #pragma unroll
        for (int i = 0; i < 4; ++i)
            #pragma unroll
            for (int j = 0; j < 4; ++j) acc[i][j] = 0.f;
        for (int k0 = 0; k0 < DDIM; k0 += 32) {
            __syncthreads();
            for (int i = tid; i < 64*32; i += 256) {
                int r = i >> 5, c = i & 31;
                wsm[r][c] = loadf(w, (size_t)(n0+r)*DDIM + k0 + c, wf32);
            }
            __syncthreads();
            #pragma unroll
            for (int k = 0; k < 32; ++k) {
                float a[4], bv[4];
                #pragma unroll
                for (int j = 0; j < 4; ++j) {
                    a[j]  = b2f(us[k0+k][tm*4+j]);
                    bv[j] = wsm[tn*4+j][k];
                }
                #pragma unroll
                for (int i = 0; i < 4; ++i)
                    #pragma unroll
                    for (int j = 0; j < 4; ++j) acc[i][j] += a[i]*bv[j];
            }
        }
        __syncthreads();   // ensure all compute done before anyone overwrites (paranoia; writes are to global)
        #pragma unroll
        for (int i = 0; i < 4; ++i) {
            int row = m0 + tm*4 + i;
            #pragma unroll
            for (int j = 0; j < 4; ++j) {
                int col = n0 + tn*4 + j;
                out[(size_t)row*DDIM + col] = acc[i][j] + loadf(bias, col, bf32);
            }
        }
    }
}

extern "C" void kernel_launch(void* const* d_in, const int* in_sizes, int n_in,
                              void* d_out, int out_size, void* d_ws, size_t ws_size,
                              hipStream_t stream) {
    (void)out_size; (void)ws_size;
    const void* x    = d_in[0];
    const int*  nidx = (const int*)d_in[1];
    const void* nw   = d_in[2];
    const void* rmat = d_in[3];
    const void* rb   = d_in[4];
    const void* cb   = d_in[5];
    const void* w    = d_in[6];
    const void* bias = d_in[7];
    const void* alpha= d_in[8];
    float* ws = (float*)d_ws;
    float* out = (float*)d_out;

    DetectArgs da;
    for (int i = 0; i < 9; ++i) { da.p[i] = d_in[i]; da.n[i] = (i < n_in) ? in_sizes[i] : 1; }

    k_detect<<<9, 256, 0, stream>>>(da, (int*)ws);
    k_rbsum<<<16, 256, 0, stream>>>(rb, ws);
    k_cb2  <<<1024, 256, 0, stream>>>(cb, ws);
    k_cb1  <<<64, 256, 0, stream>>>(cb, ws);
    k_route<<<TOK, 256, 0, stream>>>(nidx, nw, rmat, ws);
    k_stats<<<BB*(SS/TQ), 256, 0, stream>>>(ws);
    k_attn <<<dim3(SS/TQ, DDIM/DSL, BB), 256, 0, stream>>>(x, ws, alpha, out);
    k_gemm2<<<TOK/64, 256, 0, stream>>>(out, w, bias, ws);
}

// Round 5
// 1769.040 us; speedup vs baseline: 6.8108x; 6.8108x over previous
//
#include <hip/hip_runtime.h>
#include <hip/hip_bf16.h>
#include <math.h>

#define BB 4
#define SS 4096
#define DDIM 1024
#define KSEL 8
#define NR 16
#define NC 16
#define MID 256
#define RC 256
#define TOK (BB*SS)

typedef __hip_bfloat16 bf16;
typedef short short8 __attribute__((ext_vector_type(8)));
typedef float floatx4 __attribute__((ext_vector_type(4)));
#define MFMA16(a,b,c) __builtin_amdgcn_mfma_f32_16x16x32_bf16(a,b,c,0,0,0)

__device__ __forceinline__ float uihf(unsigned v) { union { unsigned i; float f; } t; t.i = v; return t.f; }
__device__ __forceinline__ float b2f(bf16 h) { return __bfloat162float(h); }
__device__ __forceinline__ float bs2f(short s) { return uihf(((unsigned)(unsigned short)s) << 16); }
__device__ __forceinline__ short f2bs(float f) {
    bf16 h = __float2bfloat16(f);
    return *reinterpret_cast<short*>(&h);
}
__device__ __forceinline__ float loadf(const void* p, size_t i, bool f32m) {
    return f32m ? ((const float*)p)[i] : b2f(((const bf16*)p)[i]);
}

// ws layout (float offsets). Total ~53.6 MB (<= 68 MB precedent from R1).
#define WS_RB   16
#define WS_CB2  4112
#define WS_CB1  8208
#define WS_CW   24592
#define WS_BIAS 286736
#define WS_QK   287760                     // short area: Q [TOK][256] then KK [TOK][256]
#define WS_WB   4482064                    // short area: W bf16 [1024][1024]
#define WS_XT   5006352                    // short area: xT bf16 [BB][DDIM][SS]

struct DetectArgs { const void* p[9]; int n[9]; };

// ---------------- dtype detector ----------------
__global__ void k_detect(DetectArgs A, int* __restrict__ flags) {
    int b = blockIdx.x;
    const unsigned short* u = (const unsigned short*)A.p[b];
    int n = A.n[b]; if (n > 4096) n = 4096;
    int tid = threadIdx.x;
    float m = 0.f;
    for (int i = tid; i < n; i += 256) {
        unsigned v = (((unsigned)u[i]) << 16) & 0x7fffffffu;
        float f = uihf(v);
        if (f == f) m = fmaxf(m, f);
    }
    for (int o = 32; o; o >>= 1) m = fmaxf(m, __shfl_xor(m, o));
    __shared__ float red[4];
    if ((tid & 63) == 0) red[tid >> 6] = m;
    __syncthreads();
    if (tid == 0) {
        float mm = fmaxf(fmaxf(red[0], red[1]), fmaxf(red[2], red[3]));
        flags[b] = (b == 1) ? 0 : (mm > 1e4f ? 1 : 0);
    }
}

// ---------------- basis sums ----------------
__global__ void k_rbsum(const void* __restrict__ rb, float* __restrict__ ws) {
    bool f32m = ((const int*)ws)[4] != 0;
    int r = blockIdx.x, m = threadIdx.x;
    size_t base = (size_t)r*DDIM*MID + m;
    float s = 0.f;
    #pragma unroll 8
    for (int d = 0; d < DDIM; ++d) s += loadf(rb, base + (size_t)d*MID, f32m);
    ws[WS_RB + r*MID + m] = s;
}

__global__ void k_cb2(const void* __restrict__ cb, float* __restrict__ ws) {
    bool f32m = ((const int*)ws)[5] != 0;
    int row = blockIdx.x*4 + (threadIdx.x >> 6);
    int lane = threadIdx.x & 63;
    size_t base = (size_t)row*DDIM;
    float s = 0.f;
    for (int i = lane; i < DDIM; i += 64) s += loadf(cb, base + i, f32m);
    for (int o = 32; o; o >>= 1) s += __shfl_down(s, o);
    if (lane == 0) ws[WS_CB2 + row] = s;
}

__global__ void k_cb1(const void* __restrict__ cb, float* __restrict__ ws) {
    bool f32m = ((const int*)ws)[5] != 0;
    int c = blockIdx.x >> 2;
    int d = ((blockIdx.x & 3) << 8) + threadIdx.x;
    size_t base = (size_t)c*MID*DDIM + d;
    float s = 0.f;
    #pragma unroll 8
    for (int m = 0; m < MID; ++m) s += loadf(cb, base + (size_t)m*DDIM, f32m);
    ws[WS_CB1 + c*DDIM + d] = s;
}

// ---------------- W -> bf16, bias -> f32 ----------------
__global__ void k_wcvt(const void* __restrict__ w, const void* __restrict__ bias,
                       float* __restrict__ ws) {
    bool wf32 = ((const int*)ws)[6] != 0, bf32 = ((const int*)ws)[7] != 0;
    short* Wb = (short*)(ws + WS_WB);
    float* biasf = ws + WS_BIAS;
    int bx = blockIdx.x, tid = threadIdx.x;
    if (bx == 512) {
        for (int i = tid; i < DDIM; i += 256) biasf[i] = loadf(bias, i, bf32);
        return;
    }
    size_t base = (size_t)bx*2048 + tid*8;
    if (wf32) {
        const float* s = (const float*)w + base;
        float4 a = *(const float4*)s, c = *(const float4*)(s + 4);
        short8 v;
        v[0]=f2bs(a.x); v[1]=f2bs(a.y); v[2]=f2bs(a.z); v[3]=f2bs(a.w);
        v[4]=f2bs(c.x); v[5]=f2bs(c.y); v[6]=f2bs(c.z); v[7]=f2bs(c.w);
        *(short8*)(Wb + base) = v;
    } else {
        *(uint4*)(Wb + base) = *(const uint4*)((const short*)w + base);
    }
}

// ---------------- x [b][s][d] -> xT bf16 [b][d][s] ----------------
__global__ void k_xt(const void* __restrict__ x, float* __restrict__ ws) {
    bool xf32 = ((const int*)ws)[0] != 0;
    __shared__ short T[64][72];
    int tid = threadIdx.x;
    int s0 = blockIdx.x*64, d0 = blockIdx.y*64, b = blockIdx.z;
    int rr = tid >> 4, c4 = (tid & 15)*4;
    #pragma unroll
    for (int it = 0; it < 4; ++it) {
        int r = rr + it*16;
        size_t off = (size_t)(b*SS + s0 + r)*DDIM + d0 + c4;
        float v[4];
        if (xf32) {
            float4 a = *(const float4*)((const float*)x + off);
            v[0]=a.x; v[1]=a.y; v[2]=a.z; v[3]=a.w;
        } else {
            const short* p = (const short*)x + off;
            #pragma unroll
            for (int j = 0; j < 4; ++j) v[j] = bs2f(p[j]);
        }
        #pragma unroll
        for (int j = 0; j < 4; ++j) T[c4+j][r] = f2bs(v[j]);
    }
    __syncthreads();
    int dr = tid >> 2, sc = (tid & 3)*16;
    short8 u0 = *(const short8*)(&T[dr][sc]);
    short8 u1 = *(const short8*)(&T[dr][sc+8]);
    short* dst = (short*)(ws + WS_XT) + ((size_t)(b*DDIM + d0 + dr))*SS + s0 + sc;
    *(short8*)dst = u0;
    *(short8*)(dst + 8) = u1;
}

// ---------------- routing: per-token q, kk, col_w ----------------
__global__ __launch_bounds__(256) void k_route(const int* __restrict__ nidx,
        const void* __restrict__ nw, const void* __restrict__ rmat,
        float* __restrict__ ws) {
    bool f2 = ((const int*)ws)[2] != 0, f3 = ((const int*)ws)[3] != 0;
    int tok = blockIdx.x, tid = threadIdx.x;
    int wid = tid >> 6, lane = tid & 63;
    __shared__ float red[4];
    __shared__ float bval;
    __shared__ int   sidx[KSEL];
    __shared__ float sw[KSEL];
    __shared__ float rec[RC];
    __shared__ float rw[NR], cw[NC];
    if (tid < KSEL) { sidx[tid] = nidx[tok*KSEL + tid]; sw[tid] = loadf(nw, tok*KSEL + tid, f2); }
    __syncthreads();

    float acc = 0.f;
    #pragma unroll 1
    for (int k = 0; k < KSEL; ++k) {
        float v = loadf(rmat, sidx[k]*RC + tid, f3);
        float r = v;
        r = fmaxf(r, __shfl_xor(r,32)); r = fmaxf(r, __shfl_xor(r,16));
        r = fmaxf(r, __shfl_xor(r, 8)); r = fmaxf(r, __shfl_xor(r, 4));
        r = fmaxf(r, __shfl_xor(r, 2)); r = fmaxf(r, __shfl_xor(r, 1));
        if (lane == 0) red[wid] = r;
        __syncthreads();
        if (tid == 0) bval = fmaxf(fmaxf(red[0],red[1]), fmaxf(red[2],red[3]));
        __syncthreads();
        float e = __expf(v - bval);
        float s = e;
        s += __shfl_xor(s,32); s += __shfl_xor(s,16); s += __shfl_xor(s,8);
        s += __shfl_xor(s, 4); s += __shfl_xor(s, 2); s += __shfl_xor(s,1);
        if (lane == 0) red[wid] = s;
        __syncthreads();
        if (tid == 0) bval = red[0]+red[1]+red[2]+red[3];
        __syncthreads();
        acc += sw[k] * e / bval;
    }
    {
        float r = acc;
        r = fmaxf(r, __shfl_xor(r,32)); r = fmaxf(r, __shfl_xor(r,16));
        r = fmaxf(r, __shfl_xor(r, 8)); r = fmaxf(r, __shfl_xor(r, 4));
        r = fmaxf(r, __shfl_xor(r, 2)); r = fmaxf(r, __shfl_xor(r, 1));
        if (lane == 0) red[wid] = r;
        __syncthreads();
        if (tid == 0) bval = fmaxf(fmaxf(red[0],red[1]), fmaxf(red[2],red[3]));
        __syncthreads();
        float e = __expf(acc - bval);
        float s = e;
        s += __shfl_xor(s,32); s += __shfl_xor(s,16); s += __shfl_xor(s,8);
        s += __shfl_xor(s, 4); s += __shfl_xor(s, 2); s += __shfl_xor(s,1);
        if (lane == 0) red[wid] = s;
        __syncthreads();
        if (tid == 0) bval = red[0]+red[1]+red[2]+red[3];
        __syncthreads();
        rec[tid] = e / bval;
    }
    __syncthreads();
    if (tid < NR) {
        float s = 0.f;
        #pragma unroll
        for (int c = 0; c < NC; ++c) s += rec[tid*NC + c];
        rw[tid] = s;
    } else if (tid < 32) {
        int c = tid - 16;
        float s = 0.f;
        #pragma unroll
        for (int r = 0; r < NR; ++r) s += rec[r*NC + c];
        cw[c] = s;
        ws[WS_CW + (size_t)tok*NC + c] = s;
    }
    __syncthreads();
    float qv = 0.f, kv = 0.f;
    #pragma unroll
    for (int r = 0; r < NR; ++r) qv += rw[r] * ws[WS_RB + r*MID + tid];
    #pragma unroll
    for (int c = 0; c < NC; ++c) kv += cw[c] * ws[WS_CB2 + c*MID + tid];
    short* Qh  = (short*)(ws + WS_QK);
    short* KKh = Qh + (size_t)TOK*MID;
    Qh [(size_t)tok*MID + tid] = f2bs(qv * 0.0625f);  // fold 1/sqrt(256)
    KKh[(size_t)tok*MID + tid] = f2bs(kv);
}

// ------- fused MFMA flash attention (no max-sub) + transform + gelu -> U f32 ----
// grid (SS/64, DDIM/256, BB), 256 thr. Wave w owns q-rows [16w,16w+16), all 256 d.
__global__ __launch_bounds__(256,2) void k_fa(const float* __restrict__ ws,
        float* __restrict__ U, const void* __restrict__ alphap) {
    __shared__ __align__(16) char smem[27392];
    short* Ks   = (short*)smem;              // [32][264] bf16, 16896 B
    short* Ps   = (short*)(smem + 16896);    // [64][40]  bf16,  5120 B
    short* cb1T = (short*)smem;              // [256][40] bf16, 20480 B (alias, epilogue only)
    short* cwsb = (short*)(smem + 22016);    // [64][40]  bf16,  5120 B

    const int tid = threadIdx.x;
    const int w = tid >> 6, lane = tid & 63, lq = lane & 15, quad = lane >> 4;
    const int q0 = blockIdx.x*64, d0 = blockIdx.y*256, b = blockIdx.z;
    const bool af32 = ((const int*)ws)[8] != 0;
    const short* Qh  = (const short*)(ws + WS_QK);
    const short* KKh = Qh + (size_t)TOK*MID;
    const short* xT  = (const short*)(ws + WS_XT);

    // stage cw rows as A-operand (k 0..15 = cw, 16..31 = 0)
    {
        int r = tid >> 2, c4 = (tid & 3)*4;
        const float* cwp = ws + WS_CW + (size_t)(b*SS + q0 + r)*NC + c4;
        short* dst = cwsb + r*40;
        #pragma unroll
        for (int j = 0; j < 4; ++j) dst[c4 + j] = f2bs(cwp[j]);
        #pragma unroll
        for (int j = 0; j < 4; ++j) dst[16 + c4 + j] = 0;
    }

    // preload Q A-frags for all 8 k-steps (rows q0+16w+lq)
    short8 qa[8];
    {
        const short* qrow = Qh + (size_t)(b*SS + q0 + w*16 + lq)*MID + quad*8;
        #pragma unroll
        for (int ks = 0; ks < 8; ++ks) qa[ks] = *(const short8*)(qrow + ks*32);
    }

    floatx4 acc[16];
    #pragma unroll
    for (int nt = 0; nt < 16; ++nt) acc[nt] = (floatx4){0.f,0.f,0.f,0.f};
    float l[4] = {0.f,0.f,0.f,0.f};

    const int ntiles = (q0 >> 5) + 2;
    for (int it = 0; it < ntiles; ++it) {
        const int t0 = it*32;
        __syncthreads();
        {   // stage K tile [32][256] -> Ks
            int r = tid >> 3, sg = (tid & 7)*32;
            const short* src = KKh + (size_t)(b*SS + t0 + r)*MID + sg;
            short* dst = Ks + r*264 + sg;
            #pragma unroll
            for (int j = 0; j < 4; ++j)
                *(short8*)(dst + j*8) = *(const short8*)(src + j*8);
        }
        __syncthreads();
        // scores S[16 q][32 t] per wave, exp+mask -> Ps (own rows, no barrier needed)
        #pragma unroll
        for (int h = 0; h < 2; ++h) {
            floatx4 s = (floatx4){0.f,0.f,0.f,0.f};
            const short* kb = Ks + (h*16 + lq)*264 + quad*8;
            #pragma unroll
            for (int ks = 0; ks < 8; ++ks)
                s = MFMA16(qa[ks], *(const short8*)(kb + ks*32), s);
            int t = t0 + h*16 + lq;
            int qg = q0 + w*16 + quad*4;
            short* pd = Ps + (w*16 + quad*4)*40 + h*16 + lq;
            #pragma unroll
            for (int r = 0; r < 4; ++r) {
                float p = (t <= qg + r) ? __expf(s[r]) : 0.f;
                l[r] += p;
                pd[r*40] = f2bs(p);
            }
        }
        // PV: A = Ps (own rows), B = xT direct from global (L2)
        short8 pa = *(const short8*)(Ps + (w*16 + lq)*40 + quad*8);
        const short* xb = xT + (size_t)(b*DDIM + d0 + lq)*SS + t0 + quad*8;
        #pragma unroll
        for (int nt = 0; nt < 16; ++nt) {
            short8 xf = *(const short8*)(xb + (size_t)nt*16*SS);
            acc[nt] = MFMA16(pa, xf, acc[nt]);
        }
    }
    // reduce l across the 16 lanes sharing each row
    #pragma unroll
    for (int r = 0; r < 4; ++r) {
        float v = l[r];
        v += __shfl_xor(v,1); v += __shfl_xor(v,2);
        v += __shfl_xor(v,4); v += __shfl_xor(v,8);
        l[r] = 1.f / v;
    }
    __syncthreads();
    // stage cb1T [256 d][16 c] (alias over Ks/Ps; k 16..31 zeroed)
    {
        const float* src = ws + WS_CB1 + d0 + tid;
        short* dst = cb1T + tid*40;
        #pragma unroll
        for (int c = 0; c < 16; ++c) dst[c] = f2bs(src[c*DDIM]);
        #pragma unroll
        for (int c = 16; c < 32; ++c) dst[c] = 0;
    }
    __syncthreads();
    float alpha = af32 ? ((const float*)alphap)[0] : bs2f(((const short*)alphap)[0]);
    short8 ca = *(const short8*)(cwsb + (w*16 + lq)*40 + quad*8);
    float* Ub = U + (size_t)(b*SS + q0 + w*16 + quad*4)*DDIM + d0 + lq;
    #pragma unroll
    for (int nt = 0; nt < 16; ++nt) {
        floatx4 tr = (floatx4){0.f,0.f,0.f,0.f};
        tr = MFMA16(ca, *(const short8*)(cb1T + (nt*16 + lq)*40 + quad*8), tr);
        #pragma unroll
        for (int r = 0; r < 4; ++r) {
            float u = acc[nt][r]*l[r] + alpha*tr[r];
            float e2 = __expf(1.5957691216f*(u + 0.044715f*u*u*u));
            float th = 1.f - 2.f/(e2 + 1.f);     // tanh, inf-safe
            Ub[(size_t)r*DDIM + nt*16] = 0.5f*u*(1.f + th);
        }
    }
}

// --------- final MFMA GEMM, in-place on d_out: out = U @ W^T + bias ----------
__global__ __launch_bounds__(256,1) void k_gemm3(float* __restrict__ out,
        const float* __restrict__ ws) {
    __shared__ __align__(16) short Us[64*1032];   // [64][1032] bf16, 129 KB
    const int tid = threadIdx.x;
    const int m0 = blockIdx.x*64;
    // stage own 64 rows of U (f32 -> bf16) before any write (in-place safe)
    for (int i = tid; i < 64*128; i += 256) {
        int row = i >> 7, k8 = (i & 127) << 3;
        const float* src = out + (size_t)(m0 + row)*DDIM + k8;
        float4 a = *(const float4*)src, c = *(const float4*)(src + 4);
        short8 v;
        v[0]=f2bs(a.x); v[1]=f2bs(a.y); v[2]=f2bs(a.z); v[3]=f2bs(a.w);
        v[4]=f2bs(c.x); v[5]=f2bs(c.y); v[6]=f2bs(c.z); v[7]=f2bs(c.w);
        *(short8*)(Us + row*1032 + k8) = v;
    }
    __syncthreads();
    const short* Wb = (const short*)(ws + WS_WB);
    const float* biasf = ws + WS_BIAS;
    const int w = tid >> 6, lane = tid & 63, lq = lane & 15, quad = lane >> 4;
    const int n0g = w*256;
    for (int mt = 0; mt < 4; ++mt) {
        short8 A[32];
        const short* ab = Us + (mt*16 + lq)*1032 + quad*8;
        #pragma unroll
        for (int ks = 0; ks < 32; ++ks) A[ks] = *(const short8*)(ab + ks*32);
        #pragma unroll 1
        for (int nt4 = 0; nt4 < 4; ++nt4) {
            floatx4 acc4[4];
            #pragma unroll
            for (int s = 0; s < 4; ++s) acc4[s] = (floatx4){0.f,0.f,0.f,0.f};
            const short* wb = Wb + (size_t)(n0g + nt4*64 + lq)*DDIM + quad*8;
            #pragma unroll
            for (int ks = 0; ks < 32; ++ks) {
                #pragma unroll
                for (int s = 0; s < 4; ++s)
                    acc4[s] = MFMA16(A[ks], *(const short8*)(wb + (size_t)s*16*DDIM + ks*32), acc4[s]);
            }
            #pragma unroll
            for (int s = 0; s < 4; ++s) {
                int col = n0g + nt4*64 + s*16 + lq;
                float bb = biasf[col];
                float* op = out + (size_t)(m0 + mt*16 + quad*4)*DDIM + col;
                #pragma unroll
                for (int r = 0; r < 4; ++r) op[(size_t)r*DDIM] = acc4[s][r] + bb;
            }
        }
    }
}

extern "C" void kernel_launch(void* const* d_in, const int* in_sizes, int n_in,
                              void* d_out, int out_size, void* d_ws, size_t ws_size,
                              hipStream_t stream) {
    (void)out_size; (void)ws_size;
    const void* x    = d_in[0];
    const int*  nidx = (const int*)d_in[1];
    const void* nw   = d_in[2];
    const void* rmat = d_in[3];
    const void* rb   = d_in[4];
    const void* cb   = d_in[5];
    const void* w    = d_in[6];
    const void* bias = d_in[7];
    const void* alpha= d_in[8];
    float* ws = (float*)d_ws;
    float* out = (float*)d_out;

    DetectArgs da;
    for (int i = 0; i < 9; ++i) { da.p[i] = d_in[i]; da.n[i] = (i < n_in) ? in_sizes[i] : 1; }

    k_detect<<<9, 256, 0, stream>>>(da, (int*)ws);
    k_rbsum<<<16, 256, 0, stream>>>(rb, ws);
    k_cb2  <<<1024, 256, 0, stream>>>(cb, ws);
    k_cb1  <<<64, 256, 0, stream>>>(cb, ws);
    k_wcvt <<<513, 256, 0, stream>>>(w, bias, ws);
    k_xt   <<<dim3(SS/64, DDIM/64, BB), 256, 0, stream>>>(x, ws);
    k_route<<<TOK, 256, 0, stream>>>(nidx, nw, rmat, ws);
    k_fa   <<<dim3(SS/64, DDIM/256, BB), 256, 0, stream>>>(ws, out, alpha);
    k_gemm3<<<TOK/64, 256, 0, stream>>>(out, ws);
}

// Round 6
// 1716.247 us; speedup vs baseline: 7.0204x; 1.0308x over previous
//
#include <hip/hip_runtime.h>
#include <hip/hip_bf16.h>
#include <math.h>

#define BB 4
#define SS 4096
#define DDIM 1024
#define KSEL 8
#define NR 16
#define NC 16
#define MID 256
#define RC 256
#define TOK (BB*SS)

typedef __hip_bfloat16 bf16;
typedef short short8 __attribute__((ext_vector_type(8)));
typedef float floatx4 __attribute__((ext_vector_type(4)));
#define MFMA16(a,b,c) __builtin_amdgcn_mfma_f32_16x16x32_bf16(a,b,c,0,0,0)

__device__ __forceinline__ float uihf(unsigned v) { union { unsigned i; float f; } t; t.i = v; return t.f; }
__device__ __forceinline__ float b2f(bf16 h) { return __bfloat162float(h); }
__device__ __forceinline__ float bs2f(short s) { return uihf(((unsigned)(unsigned short)s) << 16); }
__device__ __forceinline__ short f2bs(float f) {
    bf16 h = __float2bfloat16(f);
    return *reinterpret_cast<short*>(&h);
}
__device__ __forceinline__ float loadf(const void* p, size_t i, bool f32m) {
    return f32m ? ((const float*)p)[i] : b2f(((const bf16*)p)[i]);
}

// ws layout (float offsets)
#define WS_RB   16
#define WS_CB2  4112
#define WS_CB1  8208
#define WS_CW   24592
#define WS_BIAS 286736
#define WS_QK   287760                     // short area: Q [TOK][256] then KK [TOK][256]
#define WS_WB   4482064                    // short area: W bf16 [1024][1024]
#define WS_XT   5006352                    // short area: xT bf16 [BB][DDIM][SS]
#define WS_LV   13394960                   // [TOK] f32 softmax row sums
#define WS_P    (WS_LV + TOK)              // short area: packed causal P, 4*4160*2048 shorts
#define WS_END_FLOATS 30450704ULL          // end of WS_P area

struct DetectArgs { const void* p[9]; int n[9]; };

// ---------------- dtype detector ----------------
__global__ void k_detect(DetectArgs A, int* __restrict__ flags) {
    int b = blockIdx.x;
    const unsigned short* u = (const unsigned short*)A.p[b];
    int n = A.n[b]; if (n > 4096) n = 4096;
    int tid = threadIdx.x;
    float m = 0.f;
    for (int i = tid; i < n; i += 256) {
        unsigned v = (((unsigned)u[i]) << 16) & 0x7fffffffu;
        float f = uihf(v);
        if (f == f) m = fmaxf(m, f);
    }
    for (int o = 32; o; o >>= 1) m = fmaxf(m, __shfl_xor(m, o));
    __shared__ float red[4];
    if ((tid & 63) == 0) red[tid >> 6] = m;
    __syncthreads();
    if (tid == 0) {
        float mm = fmaxf(fmaxf(red[0], red[1]), fmaxf(red[2], red[3]));
        flags[b] = (b == 1) ? 0 : (mm > 1e4f ? 1 : 0);
    }
}

// ---------------- basis sums ----------------
__global__ void k_rbsum(const void* __restrict__ rb, float* __restrict__ ws) {
    bool f32m = ((const int*)ws)[4] != 0;
    int r = blockIdx.x, m = threadIdx.x;
    size_t base = (size_t)r*DDIM*MID + m;
    float s = 0.f;
    #pragma unroll 8
    for (int d = 0; d < DDIM; ++d) s += loadf(rb, base + (size_t)d*MID, f32m);
    ws[WS_RB + r*MID + m] = s;
}

__global__ void k_cb2(const void* __restrict__ cb, float* __restrict__ ws) {
    bool f32m = ((const int*)ws)[5] != 0;
    int row = blockIdx.x*4 + (threadIdx.x >> 6);
    int lane = threadIdx.x & 63;
    size_t base = (size_t)row*DDIM;
    float s = 0.f;
    for (int i = lane; i < DDIM; i += 64) s += loadf(cb, base + i, f32m);
    for (int o = 32; o; o >>= 1) s += __shfl_down(s, o);
    if (lane == 0) ws[WS_CB2 + row] = s;
}

__global__ void k_cb1(const void* __restrict__ cb, float* __restrict__ ws) {
    bool f32m = ((const int*)ws)[5] != 0;
    int c = blockIdx.x >> 2;
    int d = ((blockIdx.x & 3) << 8) + threadIdx.x;
    size_t base = (size_t)c*MID*DDIM + d;
    float s = 0.f;
    #pragma unroll 8
    for (int m = 0; m < MID; ++m) s += loadf(cb, base + (size_t)m*DDIM, f32m);
    ws[WS_CB1 + c*DDIM + d] = s;
}

// ---------------- W -> bf16, bias -> f32 ----------------
__global__ void k_wcvt(const void* __restrict__ w, const void* __restrict__ bias,
                       float* __restrict__ ws) {
    bool wf32 = ((const int*)ws)[6] != 0, bf32 = ((const int*)ws)[7] != 0;
    short* Wb = (short*)(ws + WS_WB);
    float* biasf = ws + WS_BIAS;
    int bx = blockIdx.x, tid = threadIdx.x;
    if (bx == 512) {
        for (int i = tid; i < DDIM; i += 256) biasf[i] = loadf(bias, i, bf32);
        return;
    }
    size_t base = (size_t)bx*2048 + tid*8;
    if (wf32) {
        const float* s = (const float*)w + base;
        float4 a = *(const float4*)s, c = *(const float4*)(s + 4);
        short8 v;
        v[0]=f2bs(a.x); v[1]=f2bs(a.y); v[2]=f2bs(a.z); v[3]=f2bs(a.w);
        v[4]=f2bs(c.x); v[5]=f2bs(c.y); v[6]=f2bs(c.z); v[7]=f2bs(c.w);
        *(short8*)(Wb + base) = v;
    } else {
        *(uint4*)(Wb + base) = *(const uint4*)((const short*)w + base);
    }
}

// ---------------- x [b][s][d] -> xT bf16 [b][d][s] ----------------
__global__ void k_xt(const void* __restrict__ x, float* __restrict__ ws) {
    bool xf32 = ((const int*)ws)[0] != 0;
    __shared__ short T[64][72];
    int tid = threadIdx.x;
    int s0 = blockIdx.x*64, d0 = blockIdx.y*64, b = blockIdx.z;
    int rr = tid >> 4, c4 = (tid & 15)*4;
    #pragma unroll
    for (int it = 0; it < 4; ++it) {
        int r = rr + it*16;
        size_t off = (size_t)(b*SS + s0 + r)*DDIM + d0 + c4;
        float v[4];
        if (xf32) {
            float4 a = *(const float4*)((const float*)x + off);
            v[0]=a.x; v[1]=a.y; v[2]=a.z; v[3]=a.w;
        } else {
            const short* p = (const short*)x + off;
            #pragma unroll
            for (int j = 0; j < 4; ++j) v[j] = bs2f(p[j]);
        }
        #pragma unroll
        for (int j = 0; j < 4; ++j) T[c4+j][r] = f2bs(v[j]);
    }
    __syncthreads();
    int dr = tid >> 2, sc = (tid & 3)*16;
    short8 u0 = *(const short8*)(&T[dr][sc]);
    short8 u1 = *(const short8*)(&T[dr][sc+8]);
    short* dst = (short*)(ws + WS_XT) + ((size_t)(b*DDIM + d0 + dr))*SS + s0 + sc;
    *(short8*)dst = u0;
    *(short8*)(dst + 8) = u1;
}

// ---------------- routing: per-token q, kk, col_w ----------------
__global__ __launch_bounds__(256) void k_route(const int* __restrict__ nidx,
        const void* __restrict__ nw, const void* __restrict__ rmat,
        float* __restrict__ ws) {
    bool f2 = ((const int*)ws)[2] != 0, f3 = ((const int*)ws)[3] != 0;
    int tok = blockIdx.x, tid = threadIdx.x;
    int wid = tid >> 6, lane = tid & 63;
    __shared__ float red[4];
    __shared__ float bval;
    __shared__ int   sidx[KSEL];
    __shared__ float sw[KSEL];
    __shared__ float rec[RC];
    __shared__ float rw[NR], cw[NC];
    if (tid < KSEL) { sidx[tid] = nidx[tok*KSEL + tid]; sw[tid] = loadf(nw, tok*KSEL + tid, f2); }
    __syncthreads();

    float acc = 0.f;
    #pragma unroll 1
    for (int k = 0; k < KSEL; ++k) {
        float v = loadf(rmat, sidx[k]*RC + tid, f3);
        float r = v;
        r = fmaxf(r, __shfl_xor(r,32)); r = fmaxf(r, __shfl_xor(r,16));
        r = fmaxf(r, __shfl_xor(r, 8)); r = fmaxf(r, __shfl_xor(r, 4));
        r = fmaxf(r, __shfl_xor(r, 2)); r = fmaxf(r, __shfl_xor(r, 1));
        if (lane == 0) red[wid] = r;
        __syncthreads();
        if (tid == 0) bval = fmaxf(fmaxf(red[0],red[1]), fmaxf(red[2],red[3]));
        __syncthreads();
        float e = __expf(v - bval);
        float s = e;
        s += __shfl_xor(s,32); s += __shfl_xor(s,16); s += __shfl_xor(s,8);
        s += __shfl_xor(s, 4); s += __shfl_xor(s, 2); s += __shfl_xor(s,1);
        if (lane == 0) red[wid] = s;
        __syncthreads();
        if (tid == 0) bval = red[0]+red[1]+red[2]+red[3];
        __syncthreads();
        acc += sw[k] * e / bval;
    }
    {
        float r = acc;
        r = fmaxf(r, __shfl_xor(r,32)); r = fmaxf(r, __shfl_xor(r,16));
        r = fmaxf(r, __shfl_xor(r, 8)); r = fmaxf(r, __shfl_xor(r, 4));
        r = fmaxf(r, __shfl_xor(r, 2)); r = fmaxf(r, __shfl_xor(r, 1));
        if (lane == 0) red[wid] = r;
        __syncthreads();
        if (tid == 0) bval = fmaxf(fmaxf(red[0],red[1]), fmaxf(red[2],red[3]));
        __syncthreads();
        float e = __expf(acc - bval);
        float s = e;
        s += __shfl_xor(s,32); s += __shfl_xor(s,16); s += __shfl_xor(s,8);
        s += __shfl_xor(s, 4); s += __shfl_xor(s, 2); s += __shfl_xor(s,1);
        if (lane == 0) red[wid] = s;
        __syncthreads();
        if (tid == 0) bval = red[0]+red[1]+red[2]+red[3];
        __syncthreads();
        rec[tid] = e / bval;
    }
    __syncthreads();
    if (tid < NR) {
        float s = 0.f;
        #pragma unroll
        for (int c = 0; c < NC; ++c) s += rec[tid*NC + c];
        rw[tid] = s;
    } else if (tid < 32) {
        int c = tid - 16;
        float s = 0.f;
        #pragma unroll
        for (int r = 0; r < NR; ++r) s += rec[r*NC + c];
        cw[c] = s;
        ws[WS_CW + (size_t)tok*NC + c] = s;
    }
    __syncthreads();
    float qv = 0.f, kv = 0.f;
    #pragma unroll
    for (int r = 0; r < NR; ++r) qv += rw[r] * ws[WS_RB + r*MID + tid];
    #pragma unroll
    for (int c = 0; c < NC; ++c) kv += cw[c] * ws[WS_CB2 + c*MID + tid];
    short* Qh  = (short*)(ws + WS_QK);
    short* KKh = Qh + (size_t)TOK*MID;
    Qh [(size_t)tok*MID + tid] = f2bs(qv * 0.0625f);  // fold 1/sqrt(256)
    KKh[(size_t)tok*MID + tid] = f2bs(kv);
}

// -------- k_score: S=Q*K^T (once), exp+mask -> packed causal P (bf16) + l ------
// grid (SS/64 [reversed], BB). Wave w owns q-rows [w*16, w*16+16).
__global__ __launch_bounds__(256) void k_score(float* __restrict__ ws) {
    __shared__ __align__(16) short Ks[32*264];   // 16.9 KB
    __shared__ __align__(16) short Ps[64*40];    //  5.1 KB
    const int tid = threadIdx.x;
    const int w = tid >> 6, lane = tid & 63, lq = lane & 15, quad = lane >> 4;
    const int qt = (gridDim.x - 1) - blockIdx.x;   // big blocks first
    const int q0 = qt*64, b = blockIdx.y;
    const short* Qh  = (const short*)(ws + WS_QK);
    const short* KKh = Qh + (size_t)TOK*MID;
    short* Pg = (short*)(ws + WS_P);

    short8 qa[8];
    {
        const short* qrow = Qh + (size_t)(b*SS + q0 + w*16 + lq)*MID + quad*8;
        #pragma unroll
        for (int ks = 0; ks < 8; ++ks) qa[ks] = *(const short8*)(qrow + ks*32);
    }
    float l[4] = {0.f,0.f,0.f,0.f};
    const int ntiles = 2*qt + 2;
    const size_t triBase = ((size_t)b*4160 + (size_t)qt*(qt+1))*2048;
    for (int it = 0; it < ntiles; ++it) {
        const int t0 = it*32;
        __syncthreads();
        {   // stage K tile [32][256]
            int r = tid >> 3, sg = (tid & 7)*32;
            const short* src = KKh + (size_t)(b*SS + t0 + r)*MID + sg;
            short* dst = Ks + r*264 + sg;
            #pragma unroll
            for (int j = 0; j < 4; ++j)
                *(short8*)(dst + j*8) = *(const short8*)(src + j*8);
        }
        __syncthreads();
        #pragma unroll
        for (int h = 0; h < 2; ++h) {
            floatx4 s = (floatx4){0.f,0.f,0.f,0.f};
            const short* kb = Ks + (h*16 + lq)*264 + quad*8;
            #pragma unroll
            for (int ks = 0; ks < 8; ++ks)
                s = MFMA16(qa[ks], *(const short8*)(kb + ks*32), s);
            int t = t0 + h*16 + lq;
            int qg = q0 + w*16 + quad*4;
            short* pd = Ps + (w*16 + quad*4)*40 + h*16 + lq;
            #pragma unroll
            for (int r = 0; r < 4; ++r) {
                float p = (t <= qg + r) ? __expf(s[r]) : 0.f;
                l[r] += p;
                pd[r*40] = f2bs(p);
            }
        }
        // wave-private copy of its 16 finished P rows to global (packed tile [64][32])
        {
            int prow = w*16 + (lane >> 2), seg = (lane & 3)*8;
            short8 v = *(const short8*)(Ps + prow*40 + seg);
            *(short8*)(Pg + triBase + (size_t)it*2048 + prow*32 + seg) = v;
        }
    }
    #pragma unroll
    for (int r = 0; r < 4; ++r) {
        float v = l[r];
        v += __shfl_xor(v,1); v += __shfl_xor(v,2);
        v += __shfl_xor(v,4); v += __shfl_xor(v,8);
        if (lq == 0) ws[WS_LV + (size_t)b*SS + q0 + w*16 + quad*4 + r] = v;
    }
}

// -------- k_pv: barrier-free streaming PV + transform + gelu -> U f32 ----------
// grid (SS/64 [reversed], DDIM/256, BB). A = P (global), B = xT (global/L2).
__global__ __launch_bounds__(256) void k_pv(const float* __restrict__ ws,
        float* __restrict__ U, const void* __restrict__ alphap) {
    __shared__ __align__(16) short cb1T[256*40];  // 20.5 KB
    __shared__ __align__(16) short cwsb[64*40];   //  5.1 KB
    const int tid = threadIdx.x;
    const int w = tid >> 6, lane = tid & 63, lq = lane & 15, quad = lane >> 4;
    const int qt = (gridDim.x - 1) - blockIdx.x;
    const int q0 = qt*64, d0 = blockIdx.y*256, b = blockIdx.z;
    const bool af32 = ((const int*)ws)[8] != 0;
    const short* xT = (const short*)(ws + WS_XT);
    const short* Pg = (const short*)(ws + WS_P);

    {   // stage cw rows as A-operand (k 0..15 = cw, 16..31 = 0)
        int r = tid >> 2, c4 = (tid & 3)*4;
        const float* cwp = ws + WS_CW + (size_t)(b*SS + q0 + r)*NC + c4;
        short* dst = cwsb + r*40;
        #pragma unroll
        for (int j = 0; j < 4; ++j) dst[c4 + j] = f2bs(cwp[j]);
        #pragma unroll
        for (int j = 0; j < 4; ++j) dst[16 + c4 + j] = 0;
    }
    {   // stage cb1T [256 d][16 c] (k 16..31 zeroed)
        const float* src = ws + WS_CB1 + d0 + tid;
        short* dst = cb1T + tid*40;
        #pragma unroll
        for (int c = 0; c < 16; ++c) dst[c] = f2bs(src[c*DDIM]);
        #pragma unroll
        for (int c = 16; c < 32; ++c) dst[c] = 0;
    }

    floatx4 acc[16];
    #pragma unroll
    for (int nt = 0; nt < 16; ++nt) acc[nt] = (floatx4){0.f,0.f,0.f,0.f};

    const int ntiles = 2*qt + 2;
    const short* pa_base = Pg + ((size_t)b*4160 + (size_t)qt*(qt+1))*2048 + (w*16 + lq)*32 + quad*8;
    const short* xb_base = xT + (size_t)(b*DDIM + d0 + lq)*SS + quad*8;
    #pragma unroll 1
    for (int it = 0; it < ntiles; ++it) {
        short8 pa = *(const short8*)(pa_base + (size_t)it*2048);
        const short* xb = xb_base + it*32;
        #pragma unroll
        for (int nt = 0; nt < 16; ++nt) {
            short8 xf = *(const short8*)(xb + (size_t)nt*16*SS);
            acc[nt] = MFMA16(pa, xf, acc[nt]);
        }
    }
    float linv[4];
    #pragma unroll
    for (int r = 0; r < 4; ++r)
        linv[r] = 1.f / ws[WS_LV + (size_t)b*SS + q0 + w*16 + quad*4 + r];

    __syncthreads();
    float alpha = af32 ? ((const float*)alphap)[0] : bs2f(((const short*)alphap)[0]);
    short8 ca = *(const short8*)(cwsb + (w*16 + lq)*40 + quad*8);
    float* Ub = U + (size_t)(b*SS + q0 + w*16 + quad*4)*DDIM + d0 + lq;
    #pragma unroll
    for (int nt = 0; nt < 16; ++nt) {
        floatx4 tr = (floatx4){0.f,0.f,0.f,0.f};
        tr = MFMA16(ca, *(const short8*)(cb1T + (nt*16 + lq)*40 + quad*8), tr);
        #pragma unroll
        for (int r = 0; r < 4; ++r) {
            float u = acc[nt][r]*linv[r] + alpha*tr[r];
            float e2 = __expf(1.5957691216f*(u + 0.044715f*u*u*u));
            float th = 1.f - 2.f/(e2 + 1.f);
            Ub[(size_t)r*DDIM + nt*16] = 0.5f*u*(1.f + th);
        }
    }
}

// ------- fallback fused attention (R5 k_fa), used only if ws too small --------
__global__ __launch_bounds__(256,2) void k_fa(const float* __restrict__ ws,
        float* __restrict__ U, const void* __restrict__ alphap) {
    __shared__ __align__(16) char smem[27392];
    short* Ks   = (short*)smem;
    short* Ps   = (short*)(smem + 16896);
    short* cb1T = (short*)smem;
    short* cwsb = (short*)(smem + 22016);

    const int tid = threadIdx.x;
    const int w = tid >> 6, lane = tid & 63, lq = lane & 15, quad = lane >> 4;
    const int q0 = blockIdx.x*64, d0 = blockIdx.y*256, b = blockIdx.z;
    const bool af32 = ((const int*)ws)[8] != 0;
    const short* Qh  = (const short*)(ws + WS_QK);
    const short* KKh = Qh + (size_t)TOK*MID;
    const short* xT  = (const short*)(ws + WS_XT);

    {
        int r = tid >> 2, c4 = (tid & 3)*4;
        const float* cwp = ws + WS_CW + (size_t)(b*SS + q0 + r)*NC + c4;
        short* dst = cwsb + r*40;
        #pragma unroll
        for (int j = 0; j < 4; ++j) dst[c4 + j] = f2bs(cwp[j]);
        #pragma unroll
        for (int j = 0; j < 4; ++j) dst[16 + c4 + j] = 0;
    }
    short8 qa[8];
    {
        const short* qrow = Qh + (size_t)(b*SS + q0 + w*16 + lq)*MID + quad*8;
        #pragma unroll
        for (int ks = 0; ks < 8; ++ks) qa[ks] = *(const short8*)(qrow + ks*32);
    }
    floatx4 acc[16];
    #pragma unroll
    for (int nt = 0; nt < 16; ++nt) acc[nt] = (floatx4){0.f,0.f,0.f,0.f};
    float l[4] = {0.f,0.f,0.f,0.f};

    const int ntiles = (q0 >> 5) + 2;
    for (int it = 0; it < ntiles; ++it) {
        const int t0 = it*32;
        __syncthreads();
        {
            int r = tid >> 3, sg = (tid & 7)*32;
            const short* src = KKh + (size_t)(b*SS + t0 + r)*MID + sg;
            short* dst = Ks + r*264 + sg;
            #pragma unroll
            for (int j = 0; j < 4; ++j)
                *(short8*)(dst + j*8) = *(const short8*)(src + j*8);
        }
        __syncthreads();
        #pragma unroll
        for (int h = 0; h < 2; ++h) {
            floatx4 s = (floatx4){0.f,0.f,0.f,0.f};
            const short* kb = Ks + (h*16 + lq)*264 + quad*8;
            #pragma unroll
            for (int ks = 0; ks < 8; ++ks)
                s = MFMA16(qa[ks], *(const short8*)(kb + ks*32), s);
            int t = t0 + h*16 + lq;
            int qg = q0 + w*16 + quad*4;
            short* pd = Ps + (w*16 + quad*4)*40 + h*16 + lq;
            #pragma unroll
            for (int r = 0; r < 4; ++r) {
                float p = (t <= qg + r) ? __expf(s[r]) : 0.f;
                l[r] += p;
                pd[r*40] = f2bs(p);
            }
        }
        short8 pa = *(const short8*)(Ps + (w*16 + lq)*40 + quad*8);
        const short* xb = xT + (size_t)(b*DDIM + d0 + lq)*SS + t0 + quad*8;
        #pragma unroll
        for (int nt = 0; nt < 16; ++nt) {
            short8 xf = *(const short8*)(xb + (size_t)nt*16*SS);
            acc[nt] = MFMA16(pa, xf, acc[nt]);
        }
    }
    #pragma unroll
    for (int r = 0; r < 4; ++r) {
        float v = l[r];
        v += __shfl_xor(v,1); v += __shfl_xor(v,2);
        v += __shfl_xor(v,4); v += __shfl_xor(v,8);
        l[r] = 1.f / v;
    }
    __syncthreads();
    {
        const float* src = ws + WS_CB1 + d0 + tid;
        short* dst = cb1T + tid*40;
        #pragma unroll
        for (int c = 0; c < 16; ++c) dst[c] = f2bs(src[c*DDIM]);
        #pragma unroll
        for (int c = 16; c < 32; ++c) dst[c] = 0;
    }
    __syncthreads();
    float alpha = af32 ? ((const float*)alphap)[0] : bs2f(((const short*)alphap)[0]);
    short8 ca = *(const short8*)(cwsb + (w*16 + lq)*40 + quad*8);
    float* Ub = U + (size_t)(b*SS + q0 + w*16 + quad*4)*DDIM + d0 + lq;
    #pragma unroll
    for (int nt = 0; nt < 16; ++nt) {
        floatx4 tr = (floatx4){0.f,0.f,0.f,0.f};
        tr = MFMA16(ca, *(const short8*)(cb1T + (nt*16 + lq)*40 + quad*8), tr);
        #pragma unroll
        for (int r = 0; r < 4; ++r) {
            float u = acc[nt][r]*l[r] + alpha*tr[r];
            float e2 = __expf(1.5957691216f*(u + 0.044715f*u*u*u));
            float th = 1.f - 2.f/(e2 + 1.f);
            Ub[(size_t)r*DDIM + nt*16] = 0.5f*u*(1.f + th);
        }
    }
}

// --------- final MFMA GEMM, in-place on d_out: out = U @ W^T + bias ----------
__global__ __launch_bounds__(256,1) void k_gemm3(float* __restrict__ out,
        const float* __restrict__ ws) {
    __shared__ __align__(16) short Us[64*1032];   // 129 KB
    const int tid = threadIdx.x;
    const int m0 = blockIdx.x*64;
    for (int i = tid; i < 64*128; i += 256) {
        int row = i >> 7, k8 = (i & 127) << 3;
        const float* src = out + (size_t)(m0 + row)*DDIM + k8;
        float4 a = *(const float4*)src, c = *(const float4*)(src + 4);
        short8 v;
        v[0]=f2bs(a.x); v[1]=f2bs(a.y); v[2]=f2bs(a.z); v[3]=f2bs(a.w);
        v[4]=f2bs(c.x); v[5]=f2bs(c.y); v[6]=f2bs(c.z); v[7]=f2bs(c.w);
        *(short8*)(Us + row*1032 + k8) = v;
    }
    __syncthreads();
    const short* Wb = (const short*)(ws + WS_WB);
    const float* biasf = ws + WS_BIAS;
    const int w = tid >> 6, lane = tid & 63, lq = lane & 15, quad = lane >> 4;
    const int n0g = w*256;
    for (int mt = 0; mt < 4; ++mt) {
        short8 A[32];
        const short* ab = Us + (mt*16 + lq)*1032 + quad*8;
        #pragma unroll
        for (int ks = 0; ks < 32; ++ks) A[ks] = *(const short8*)(ab + ks*32);
        #pragma unroll 1
        for (int nt4 = 0; nt4 < 4; ++nt4) {
            floatx4 acc4[4];
            #pragma unroll
            for (int s = 0; s < 4; ++s) acc4[s] = (floatx4){0.f,0.f,0.f,0.f};
            const short* wb = Wb + (size_t)(n0g + nt4*64 + lq)*DDIM + quad*8;
            #pragma unroll
            for (int ks = 0; ks < 32; ++ks) {
                #pragma unroll
                for (int s = 0; s < 4; ++s)
                    acc4[s] = MFMA16(A[ks], *(const short8*)(wb + (size_t)s*16*DDIM + ks*32), acc4[s]);
            }
            #pragma unroll
            for (int s = 0; s < 4; ++s) {
                int col = n0g + nt4*64 + s*16 + lq;
                float bb = biasf[col];
                float* op = out + (size_t)(m0 + mt*16 + quad*4)*DDIM + col;
                #pragma unroll
                for (int r = 0; r < 4; ++r) op[(size_t)r*DDIM] = acc4[s][r] + bb;
            }
        }
    }
}

extern "C" void kernel_launch(void* const* d_in, const int* in_sizes, int n_in,
                              void* d_out, int out_size, void* d_ws, size_t ws_size,
                              hipStream_t stream) {
    (void)out_size;
    const void* x    = d_in[0];
    const int*  nidx = (const int*)d_in[1];
    const void* nw   = d_in[2];
    const void* rmat = d_in[3];
    const void* rb   = d_in[4];
    const void* cb   = d_in[5];
    const void* w    = d_in[6];
    const void* bias = d_in[7];
    const void* alpha= d_in[8];
    float* ws = (float*)d_ws;
    float* out = (float*)d_out;
    const bool bigws = ws_size >= WS_END_FLOATS*4ULL;   // host-constant: graph-safe

    DetectArgs da;
    for (int i = 0; i < 9; ++i) { da.p[i] = d_in[i]; da.n[i] = (i < n_in) ? in_sizes[i] : 1; }

    k_detect<<<9, 256, 0, stream>>>(da, (int*)ws);
    k_rbsum<<<16, 256, 0, stream>>>(rb, ws);
    k_cb2  <<<1024, 256, 0, stream>>>(cb, ws);
    k_cb1  <<<64, 256, 0, stream>>>(cb, ws);
    k_wcvt <<<513, 256, 0, stream>>>(w, bias, ws);
    k_xt   <<<dim3(SS/64, DDIM/64, BB), 256, 0, stream>>>(x, ws);
    k_route<<<TOK, 256, 0, stream>>>(nidx, nw, rmat, ws);
    if (bigws) {
        k_score<<<dim3(SS/64, BB), 256, 0, stream>>>(ws);
        k_pv   <<<dim3(SS/64, DDIM/256, BB), 256, 0, stream>>>(ws, out, alpha);
    } else {
        k_fa   <<<dim3(SS/64, DDIM/256, BB), 256, 0, stream>>>(ws, out, alpha);
    }
    k_gemm3<<<TOK/64, 256, 0, stream>>>(out, ws);
}